// Round 9
// baseline (1138.441 us; speedup 1.0000x reference)
//
#include <hip/hip_runtime.h>
#include <hip/hip_cooperative_groups.h>

namespace cg = cooperative_groups;

#define N_NODES   50000
#define N_EDGES   600000
#define HID       128
#define N_GRAPHS  128
#define N_CLASSES 5
#define NTHR      256
#define NCHUNK    ((N_NODES + 255) / 256)   // 196
#define SCAN_BLK  NCHUNK

struct Args {
    const float* x; const int* src; const int* dst; const int* batch;
    const float* W1; const float* b1; const float* W2; const float* b2;
    const float* W3; const float* b3; const float* Wl; const float* bl;
    float* out;
    int* ideg; int* cursor; float* fpsum; int* gcnt; float* dis;
    int* rowst; int* col; int* bsum; float* bufA; float* bufB;
};

// ======================= shared phase bodies =======================

template <bool POOL>
__device__ __forceinline__ void agg_body(const float* __restrict__ t,
                                         const float* __restrict__ dis,
                                         const int* __restrict__ rowst,
                                         const int* __restrict__ col,
                                         const float* __restrict__ bias,
                                         const int* __restrict__ batch,
                                         float* __restrict__ fpsum,
                                         float* __restrict__ outp,
                                         int d0, int dstride) {
    int lane = threadIdx.x & 63;
    const float2* t2 = (const float2*)t;
    float2 bv = ((const float2*)bias)[lane];
    for (int d = d0; d < N_NODES; d += dstride) {
        float dd = dis[d];
        int j0 = rowst[d], j1 = rowst[d + 1];
        float2 self = t2[(size_t)d * 64 + lane];
        float ax0 = self.x, ay0 = self.y;
        float ax1 = 0.f, ay1 = 0.f, ax2 = 0.f, ay2 = 0.f, ax3 = 0.f, ay3 = 0.f;
        int j = j0;
        for (; j + 3 < j1; j += 4) {
            int s0 = col[j], s1 = col[j + 1], s2 = col[j + 2], s3 = col[j + 3];
            float2 v0 = t2[(size_t)s0 * 64 + lane];
            float2 v1 = t2[(size_t)s1 * 64 + lane];
            float2 v2 = t2[(size_t)s2 * 64 + lane];
            float2 v3 = t2[(size_t)s3 * 64 + lane];
            ax0 += v0.x; ay0 += v0.y;
            ax1 += v1.x; ay1 += v1.y;
            ax2 += v2.x; ay2 += v2.y;
            ax3 += v3.x; ay3 += v3.y;
        }
        for (; j < j1; ++j) {
            int s = col[j];
            float2 v = t2[(size_t)s * 64 + lane];
            ax0 += v.x; ay0 += v.y;
        }
        float sx = (ax0 + ax1) + (ax2 + ax3);
        float sy = (ay0 + ay1) + (ay2 + ay3);
        float zx = fmaxf(fmaf(dd, sx, bv.x), 0.f);
        float zy = fmaxf(fmaf(dd, sy, bv.y), 0.f);
        if (POOL) {
            int g = batch[d];
            atomicAdd(&fpsum[g * HID + 2 * lane], zx);
            atomicAdd(&fpsum[g * HID + 2 * lane + 1], zy);
        } else {
            float2 o; o.x = zx; o.y = zy;
            ((float2*)outp)[(size_t)d * 64 + lane] = o;
        }
    }
}

// 64 rows per virtual block, 8x4 micro-tile, k-chunk 4, double-buffered LDS W stage.
__device__ __forceinline__ void gemm_body(const float* __restrict__ h,
                                          const float* __restrict__ W,
                                          const float* __restrict__ dis,
                                          float* __restrict__ outp,
                                          float* Ws, int vb0, int vbstride) {
    int t  = threadIdx.x;
    int tc = t & 31;
    int tr = t >> 5;
    int off = t * 2, skk = off >> 7, sc = off & 127;
    for (int vb = vb0; vb < (N_NODES + 63) / 64; vb += vbstride) {
        int row0 = vb * 64 + tr * 8;
        float acc[8][4];
#pragma unroll
        for (int r = 0; r < 8; ++r)
#pragma unroll
            for (int c = 0; c < 4; ++c) acc[r][c] = 0.f;
        *(float2*)&Ws[0 * 512 + skk * HID + sc] = *(const float2*)&W[skk * HID + sc];
        int buf = 0;
        for (int k0 = 0; k0 < HID; k0 += 4) {
            float4 hr[8];
#pragma unroll
            for (int r = 0; r < 8; ++r) {
                int row = row0 + r; if (row >= N_NODES) row = N_NODES - 1;
                hr[r] = *(const float4*)&h[(size_t)row * HID + k0];
            }
            __syncthreads();
            if (k0 + 4 < HID)
                *(float2*)&Ws[(buf ^ 1) * 512 + skk * HID + sc] =
                    *(const float2*)&W[(k0 + 4 + skk) * HID + sc];
#pragma unroll
            for (int kk = 0; kk < 4; ++kk) {
                float4 wv = *(const float4*)&Ws[buf * 512 + kk * HID + tc * 4];
#pragma unroll
                for (int r = 0; r < 8; ++r) {
                    float hv = ((const float*)&hr[r])[kk];
                    acc[r][0] = fmaf(hv, wv.x, acc[r][0]);
                    acc[r][1] = fmaf(hv, wv.y, acc[r][1]);
                    acc[r][2] = fmaf(hv, wv.z, acc[r][2]);
                    acc[r][3] = fmaf(hv, wv.w, acc[r][3]);
                }
            }
            buf ^= 1;
        }
#pragma unroll
        for (int r = 0; r < 8; ++r) {
            int row = row0 + r;
            if (row < N_NODES) {
                float dd = dis[row];
                float4 o;
                o.x = dd * acc[r][0]; o.y = dd * acc[r][1];
                o.z = dd * acc[r][2]; o.w = dd * acc[r][3];
                *(float4*)&outp[(size_t)row * HID + tc * 4] = o;
            }
        }
        __syncthreads();
    }
}

__device__ __forceinline__ void gemm_in_body(const float* __restrict__ x,
                                             const float* __restrict__ W,
                                             const float* __restrict__ dis,
                                             float* __restrict__ outp,
                                             int i0, int istride) {
    for (int idx = i0; idx < N_NODES * 32; idx += istride) {
        int row = idx >> 5, c4 = (idx & 31) * 4;
        float x0 = x[row * 3 + 0], x1 = x[row * 3 + 1], x2 = x[row * 3 + 2];
        float4 w0 = *(const float4*)&W[0 * HID + c4];
        float4 w1 = *(const float4*)&W[1 * HID + c4];
        float4 w2 = *(const float4*)&W[2 * HID + c4];
        float dd = dis[row];
        float4 o;
        o.x = dd * fmaf(x2, w2.x, fmaf(x1, w1.x, x0 * w0.x));
        o.y = dd * fmaf(x2, w2.y, fmaf(x1, w1.y, x0 * w0.y));
        o.z = dd * fmaf(x2, w2.z, fmaf(x1, w1.z, x0 * w0.z));
        o.w = dd * fmaf(x2, w2.w, fmaf(x1, w1.w, x0 * w0.w));
        *(float4*)&outp[(size_t)row * HID + c4] = o;
    }
}

__device__ __forceinline__ void final_body(const float* __restrict__ fpsum,
                                           const int* __restrict__ gcnt,
                                           const float* __restrict__ Wl,
                                           const float* __restrict__ bl,
                                           float* __restrict__ outp,
                                           int i0, int istride) {
    for (int idx = i0; idx < N_GRAPHS * N_CLASSES; idx += istride) {
        int g = idx / N_CLASSES, c = idx % N_CLASSES;
        float inv = 1.0f / (float)max(gcnt[g], 1);
        float acc = bl[c];
        for (int f = 0; f < HID; ++f)
            acc = fmaf(fpsum[g * HID + f] * inv, Wl[f * N_CLASSES + c], acc);
        outp[idx] = acc;
    }
}

// ======================= cooperative mega-kernel =======================

__global__ void __launch_bounds__(NTHR, 4) k_mega(Args a) {
    cg::grid_group grid = cg::this_grid();
    __shared__ int   s1[256];
    __shared__ int   s2[256];
    __shared__ float Ws[2 * 512];
    __shared__ int   sgo[N_GRAPHS + 1];
    int t = threadIdx.x;
    int nb = gridDim.x;
    int gtid = blockIdx.x * NTHR + t;
    int gt = nb * NTHR;

    // ---- P0: zero accumulators; gcnt via binary search (block 0)
    for (int i = gtid; i < N_NODES; i += gt) { a.ideg[i] = 0; a.cursor[i] = 0; }
    for (int i = gtid; i < N_GRAPHS * HID; i += gt) a.fpsum[i] = 0.f;
    if (blockIdx.x == 0) {
        if (t <= N_GRAPHS) {
            int lo = 0, hi = N_NODES;
            while (lo < hi) { int mid = (lo + hi) >> 1; if (a.batch[mid] < t) lo = mid + 1; else hi = mid; }
            sgo[t] = lo;
        }
        __syncthreads();
        if (t < N_GRAPHS) a.gcnt[t] = sgo[t + 1] - sgo[t];
    }
    grid.sync();

    // ---- P1: in-degree
    for (int e = gtid; e < N_EDGES; e += gt) atomicAdd(&a.ideg[a.dst[e]], 1);
    grid.sync();

    // ---- P2: per-chunk degree sums + dis
    for (int c = blockIdx.x; c < NCHUNK; c += nb) {
        int i = c * 256 + t;
        int v = (i < N_NODES) ? a.ideg[i] : 0;
        if (i < N_NODES) a.dis[i] = 1.0f / sqrtf((float)v + 1.0f);
        s1[t] = v; __syncthreads();
        for (int o = 128; o > 0; o >>= 1) { if (t < o) s1[t] += s1[t + o]; __syncthreads(); }
        if (t == 0) a.bsum[c] = s1[0];
        __syncthreads();
    }
    grid.sync();

    // ---- P3: redundant per-block bsum scan -> row_start; + layer-1 GEMM
    {
        int v = (t < NCHUNK) ? a.bsum[t] : 0;
        s1[t] = v; __syncthreads();
        for (int o = 1; o < 256; o <<= 1) {
            int u = (t >= o) ? s1[t - o] : 0; __syncthreads();
            s1[t] += u; __syncthreads();
        }
        s2[t] = s1[t] - v;
        int total = s1[255];
        __syncthreads();
        for (int c = blockIdx.x; c < NCHUNK; c += nb) {
            int base = s2[c];
            int i = c * 256 + t;
            int v2 = (i < N_NODES) ? a.ideg[i] : 0;
            s1[t] = v2; __syncthreads();
            for (int o = 1; o < 256; o <<= 1) {
                int u = (t >= o) ? s1[t - o] : 0; __syncthreads();
                s1[t] += u; __syncthreads();
            }
            if (i < N_NODES) a.rowst[i] = base + s1[t] - v2;
            __syncthreads();
        }
        if (gtid == 0) a.rowst[N_NODES] = total;
        gemm_in_body(a.x, a.W1, a.dis, a.bufA, gtid, gt);
    }
    grid.sync();

    // ---- P4: CSR fill
    for (int e = gtid; e < N_EDGES; e += gt) {
        int d = a.dst[e];
        int pos = atomicAdd(&a.cursor[d], 1);
        a.col[a.rowst[d] + pos] = a.src[e];
    }
    grid.sync();

    // ---- layers
    int wid = threadIdx.x >> 6;
    agg_body<false>(a.bufA, a.dis, a.rowst, a.col, a.b1, a.batch, a.fpsum, a.bufB,
                    blockIdx.x * 4 + wid, nb * 4);
    grid.sync();
    gemm_body(a.bufB, a.W2, a.dis, a.bufA, Ws, blockIdx.x, nb);
    grid.sync();
    agg_body<false>(a.bufA, a.dis, a.rowst, a.col, a.b2, a.batch, a.fpsum, a.bufB,
                    blockIdx.x * 4 + wid, nb * 4);
    grid.sync();
    gemm_body(a.bufB, a.W3, a.dis, a.bufA, Ws, blockIdx.x, nb);
    grid.sync();
    agg_body<true>(a.bufA, a.dis, a.rowst, a.col, a.b3, a.batch, a.fpsum, nullptr,
                   blockIdx.x * 4 + wid, nb * 4);
    grid.sync();

    // ---- P10: classifier
    final_body(a.fpsum, a.gcnt, a.Wl, a.bl, a.out, gtid, gt);
}

// ======================= fallback pipeline (proven R6) =======================

__global__ void k_deg(const int* __restrict__ dst, int* __restrict__ ideg, int E) {
    int i = blockIdx.x * blockDim.x + threadIdx.x;
    if (i < E) atomicAdd(&ideg[dst[i]], 1);
}

__global__ void k_scan_part(const int* __restrict__ ideg, int* __restrict__ bsum,
                            float* __restrict__ dis, int n) {
    __shared__ int s[256];
    int t = threadIdx.x;
    int i = blockIdx.x * 256 + t;
    int v = (i < n) ? ideg[i] : 0;
    if (i < n) dis[i] = 1.0f / sqrtf((float)v + 1.0f);
    s[t] = v;
    __syncthreads();
    for (int o = 128; o > 0; o >>= 1) { if (t < o) s[t] += s[t + o]; __syncthreads(); }
    if (t == 0) bsum[blockIdx.x] = s[0];
}

__global__ void k_scan_bsum(const int* __restrict__ bsum, int* __restrict__ boff, int B) {
    __shared__ int s[256];
    int t = threadIdx.x;
    int v = (t < B) ? bsum[t] : 0;
    s[t] = v;
    __syncthreads();
    for (int o = 1; o < 256; o <<= 1) {
        int u = (t >= o) ? s[t - o] : 0; __syncthreads();
        s[t] += u; __syncthreads();
    }
    if (t < B) boff[t] = s[t] - v;
    if (t == 255) boff[B] = s[255];
}

__global__ void k_scan_write(const int* __restrict__ ideg, const int* __restrict__ boff,
                             int* __restrict__ row_start, int n, int B) {
    __shared__ int s[256];
    int t = threadIdx.x;
    int i = blockIdx.x * 256 + t;
    int v = (i < n) ? ideg[i] : 0;
    s[t] = v;
    __syncthreads();
    for (int o = 1; o < 256; o <<= 1) {
        int u = (t >= o) ? s[t - o] : 0; __syncthreads();
        s[t] += u; __syncthreads();
    }
    if (i < n) row_start[i] = boff[blockIdx.x] + s[t] - v;
    if (blockIdx.x == 0 && t == 0) row_start[n] = boff[B];
}

__global__ void k_fill(const int* __restrict__ src, const int* __restrict__ dst,
                       const int* __restrict__ row_start, int* __restrict__ cursor,
                       int* __restrict__ col, int E) {
    int i = blockIdx.x * blockDim.x + threadIdx.x;
    if (i < E) {
        int d = dst[i];
        int pos = atomicAdd(&cursor[d], 1);
        col[row_start[d] + pos] = src[i];
    }
}

__global__ void k_goff(const int* __restrict__ batch, int* __restrict__ gcnt, int n) {
    __shared__ int s[N_GRAPHS + 1];
    int t = threadIdx.x;
    if (t <= N_GRAPHS) {
        int lo = 0, hi = n;
        while (lo < hi) { int mid = (lo + hi) >> 1; if (batch[mid] < t) lo = mid + 1; else hi = mid; }
        s[t] = lo;
    }
    __syncthreads();
    if (t < N_GRAPHS) gcnt[t] = s[t + 1] - s[t];
}

__global__ void k_zero(float* __restrict__ fpsum) {
    fpsum[blockIdx.x * blockDim.x + threadIdx.x] = 0.f;
}

__global__ void k_gemm_in(const float* __restrict__ x, const float* __restrict__ W,
                          const float* __restrict__ dis, float* __restrict__ out, int n) {
    int idx = blockIdx.x * blockDim.x + threadIdx.x;
    if (idx >= n * 32) return;
    gemm_in_body(x, W, dis, out, idx, n * 32 + 999999999);  // single iteration
}

__global__ __launch_bounds__(256) void k_gemm64(const float* __restrict__ h,
                                                const float* __restrict__ W,
                                                const float* __restrict__ dis,
                                                float* __restrict__ out) {
    __shared__ float Ws[2 * 512];
    gemm_body(h, W, dis, out, Ws, blockIdx.x, (N_NODES + 63) / 64 + 1);
}

__global__ __launch_bounds__(256) void k_agg(const float* __restrict__ t,
                                             const float* __restrict__ dis,
                                             const int* __restrict__ row_start,
                                             const int* __restrict__ col,
                                             const float* __restrict__ bias,
                                             float* __restrict__ out) {
    int wid = threadIdx.x >> 6;
    int d = blockIdx.x * 4 + wid;
    if (d >= N_NODES) return;
    agg_body<false>(t, dis, row_start, col, bias, nullptr, nullptr, out,
                    d, N_NODES + 1);  // single iteration
}

__global__ __launch_bounds__(256) void k_agg_pool(const float* __restrict__ t,
                                                  const float* __restrict__ dis,
                                                  const int* __restrict__ row_start,
                                                  const int* __restrict__ col,
                                                  const float* __restrict__ bias,
                                                  const int* __restrict__ batch,
                                                  float* __restrict__ fpsum) {
    int wid = threadIdx.x >> 6;
    int d = blockIdx.x * 4 + wid;
    if (d >= N_NODES) return;
    agg_body<true>(t, dis, row_start, col, bias, batch, fpsum, nullptr,
                   d, N_NODES + 1);
}

__global__ void k_final(const float* __restrict__ fpsum, const int* __restrict__ gcnt,
                        const float* __restrict__ Wl, const float* __restrict__ bl,
                        float* __restrict__ out) {
    int idx = blockIdx.x * blockDim.x + threadIdx.x;
    if (idx >= N_GRAPHS * N_CLASSES) return;
    final_body(fpsum, gcnt, Wl, bl, out, idx, N_GRAPHS * N_CLASSES + 1);
}

// ======================= launcher =======================

extern "C" void kernel_launch(void* const* d_in, const int* in_sizes, int n_in,
                              void* d_out, int out_size, void* d_ws, size_t ws_size,
                              hipStream_t stream) {
    Args a;
    a.x     = (const float*)d_in[0];
    a.src   = (const int*)d_in[1];
    a.dst   = (const int*)d_in[1] + N_EDGES;
    a.batch = (const int*)d_in[2];
    a.W1 = (const float*)d_in[3];  a.b1 = (const float*)d_in[4];
    a.W2 = (const float*)d_in[5];  a.b2 = (const float*)d_in[6];
    a.W3 = (const float*)d_in[7];  a.b3 = (const float*)d_in[8];
    a.Wl = (const float*)d_in[9];  a.bl = (const float*)d_in[10];
    a.out = (float*)d_out;

    char* ws = (char*)d_ws;
    size_t off = 0;
    auto alloc = [&](size_t bytes) -> void* {
        void* p = ws + off;
        off += (bytes + 255) & ~(size_t)255;
        return p;
    };
    a.ideg   = (int*)alloc((size_t)N_NODES * 4);
    a.cursor = (int*)alloc((size_t)N_NODES * 4);
    a.fpsum  = (float*)alloc((size_t)N_GRAPHS * HID * 4);
    a.gcnt   = (int*)alloc((size_t)N_GRAPHS * 4);
    a.dis    = (float*)alloc((size_t)N_NODES * 4);
    a.rowst  = (int*)alloc((size_t)(N_NODES + 1) * 4);
    a.col    = (int*)alloc((size_t)N_EDGES * 4);
    a.bsum   = (int*)alloc((size_t)NCHUNK * 4);
    int* boff = (int*)alloc((size_t)(NCHUNK + 1) * 4);
    a.bufA   = (float*)alloc((size_t)N_NODES * HID * 4);
    a.bufB   = (float*)alloc((size_t)N_NODES * HID * 4);

    // --- try cooperative mega-kernel, clamped to guaranteed co-residency ---
    int occ = 0;
    hipError_t qerr = hipOccupancyMaxActiveBlocksPerMultiprocessor(
        &occ, (const void*)k_mega, NTHR, 0);
    hipError_t lerr = hipErrorUnknown;
    if (qerr == hipSuccess && occ > 0) {
        int nblk = occ * 256;               // 256 CUs on MI355X
        if (nblk > 1024) nblk = 1024;
        if (nblk >= 256) {                  // need >= NCHUNK blocks for scan phases
            void* kargs[] = { &a };
            lerr = hipLaunchCooperativeKernel((const void*)k_mega, dim3(nblk),
                                              dim3(NTHR), kargs, 0, stream);
        }
    }
    if (lerr == hipSuccess) return;

    // --- fallback: proven multi-kernel pipeline ---
    const int tpb = 256;
    const int N = N_NODES, E = N_EDGES;
    hipMemsetAsync(a.ideg, 0, (size_t)N * 4, stream);
    hipMemsetAsync(a.cursor, 0, (size_t)N * 4, stream);
    k_zero<<<N_GRAPHS * HID / tpb, tpb, 0, stream>>>(a.fpsum);
    k_deg<<<(E + tpb - 1) / tpb, tpb, 0, stream>>>(a.dst, a.ideg, E);
    k_scan_part<<<NCHUNK, 256, 0, stream>>>(a.ideg, a.bsum, a.dis, N);
    k_scan_bsum<<<1, 256, 0, stream>>>(a.bsum, boff, NCHUNK);
    k_scan_write<<<NCHUNK, 256, 0, stream>>>(a.ideg, boff, a.rowst, N, NCHUNK);
    k_fill<<<(E + tpb - 1) / tpb, tpb, 0, stream>>>(a.src, a.dst, a.rowst, a.cursor, a.col, E);
    k_goff<<<1, 256, 0, stream>>>(a.batch, a.gcnt, N);
    k_gemm_in<<<(N * 32 + tpb - 1) / tpb, tpb, 0, stream>>>(a.x, a.W1, a.dis, a.bufA, N);
    k_agg<<<(N + 3) / 4, 256, 0, stream>>>(a.bufA, a.dis, a.rowst, a.col, a.b1, a.bufB);
    k_gemm64<<<(N + 63) / 64, 256, 0, stream>>>(a.bufB, a.W2, a.dis, a.bufA);
    k_agg<<<(N + 3) / 4, 256, 0, stream>>>(a.bufA, a.dis, a.rowst, a.col, a.b2, a.bufB);
    k_gemm64<<<(N + 63) / 64, 256, 0, stream>>>(a.bufB, a.W3, a.dis, a.bufA);
    k_agg_pool<<<(N + 3) / 4, 256, 0, stream>>>(a.bufA, a.dis, a.rowst, a.col, a.b3, a.batch, a.fpsum);
    k_final<<<(N_GRAPHS * N_CLASSES + tpb - 1) / tpb, tpb, 0, stream>>>(a.fpsum, a.gcnt, a.Wl, a.bl, a.out);
}

// Round 10
// 438.172 us; speedup vs baseline: 2.5982x; 2.5982x over previous
//
#include <hip/hip_runtime.h>

#define N_NODES   50000
#define N_EDGES   600000
#define HID       128
#define N_GRAPHS  128
#define N_CLASSES 5
#define NCHUNK    ((N_NODES + 255) / 256)   // 196

// --- in-degree by dst ---
__global__ void k_deg(const int* __restrict__ dst, int* __restrict__ ideg, int E) {
    int i = blockIdx.x * blockDim.x + threadIdx.x;
    if (i < E) atomicAdd(&ideg[dst[i]], 1);
}

// --- per-chunk degree sums + dis = rsqrt(deg+1) ---
__global__ void k_scan_part(const int* __restrict__ ideg, int* __restrict__ bsum,
                            float* __restrict__ dis, int n) {
    __shared__ int s[256];
    int t = threadIdx.x;
    int i = blockIdx.x * 256 + t;
    int v = (i < n) ? ideg[i] : 0;
    if (i < n) dis[i] = 1.0f / sqrtf((float)v + 1.0f);
    s[t] = v;
    __syncthreads();
    for (int o = 128; o > 0; o >>= 1) { if (t < o) s[t] += s[t + o]; __syncthreads(); }
    if (t == 0) bsum[blockIdx.x] = s[0];
}

// --- single block: scan chunk sums -> boff, AND graph counts via binary search ---
__global__ void k_scan_bsum_goff(const int* __restrict__ bsum, int* __restrict__ boff,
                                 const int* __restrict__ batch, int* __restrict__ gcnt) {
    __shared__ int s[256];
    __shared__ int sgo[N_GRAPHS + 1];
    int t = threadIdx.x;
    int v = (t < NCHUNK) ? bsum[t] : 0;
    s[t] = v;
    __syncthreads();
    for (int o = 1; o < 256; o <<= 1) {
        int u = (t >= o) ? s[t - o] : 0; __syncthreads();
        s[t] += u; __syncthreads();
    }
    if (t < NCHUNK) boff[t] = s[t] - v;
    if (t == 255) boff[NCHUNK] = s[255];
    if (t <= N_GRAPHS) {
        int lo = 0, hi = N_NODES;
        while (lo < hi) { int mid = (lo + hi) >> 1; if (batch[mid] < t) lo = mid + 1; else hi = mid; }
        sgo[t] = lo;
    }
    __syncthreads();
    if (t < N_GRAPHS) gcnt[t] = sgo[t + 1] - sgo[t];
}

// --- per-chunk exclusive scan -> row_start ---
__global__ void k_scan_write(const int* __restrict__ ideg, const int* __restrict__ boff,
                             int* __restrict__ row_start, int n) {
    __shared__ int s[256];
    int t = threadIdx.x;
    int i = blockIdx.x * 256 + t;
    int v = (i < n) ? ideg[i] : 0;
    s[t] = v;
    __syncthreads();
    for (int o = 1; o < 256; o <<= 1) {
        int u = (t >= o) ? s[t - o] : 0; __syncthreads();
        s[t] += u; __syncthreads();
    }
    if (i < n) row_start[i] = boff[blockIdx.x] + s[t] - v;
    if (blockIdx.x == 0 && t == 0) row_start[n] = boff[NCHUNK];
}

// --- fused: CSR fill (first 600k threads) + layer-1 GEMM (all 1.6M threads) ---
// grid = 6250 blocks * 256 = 1.6M = N_NODES*32 exactly; E < 1.6M.
__global__ void k_fill_gin(const int* __restrict__ src, const int* __restrict__ dst,
                           const int* __restrict__ rowst, int* __restrict__ cursor,
                           int* __restrict__ col,
                           const float* __restrict__ x, const float* __restrict__ W1,
                           const float* __restrict__ dis, float* __restrict__ out) {
    int gtid = blockIdx.x * 256 + threadIdx.x;
    if (gtid < N_EDGES) {
        int d = dst[gtid];
        int pos = atomicAdd(&cursor[d], 1);
        col[rowst[d] + pos] = src[gtid];
    }
    if (gtid < N_NODES * 32) {
        int row = gtid >> 5, c4 = (gtid & 31) * 4;
        float x0 = x[row * 3 + 0], x1 = x[row * 3 + 1], x2 = x[row * 3 + 2];
        float4 w0 = *(const float4*)&W1[0 * HID + c4];
        float4 w1 = *(const float4*)&W1[1 * HID + c4];
        float4 w2 = *(const float4*)&W1[2 * HID + c4];
        float dd = dis[row];
        float4 o;
        o.x = dd * fmaf(x2, w2.x, fmaf(x1, w1.x, x0 * w0.x));
        o.y = dd * fmaf(x2, w2.y, fmaf(x1, w1.y, x0 * w0.y));
        o.z = dd * fmaf(x2, w2.z, fmaf(x1, w1.z, x0 * w0.z));
        o.w = dd * fmaf(x2, w2.w, fmaf(x1, w1.w, x0 * w0.w));
        *(float4*)&out[(size_t)row * HID + c4] = o;
    }
}

// --- 128x128 GEMM (R6-proven): out = dis[:,None] * (h @ W), 64 rows/block ---
__global__ __launch_bounds__(256) void k_gemm64(const float* __restrict__ h,
                                                const float* __restrict__ W,
                                                const float* __restrict__ dis,
                                                float* __restrict__ out, int n) {
    __shared__ float Ws[2][8 * HID];
    int t  = threadIdx.x;
    int tc = t & 31;
    int tr = t >> 5;
    int rb = blockIdx.x * 64;
    int row0 = rb + tr * 8;
    int skk = t >> 5, sc4 = (t & 31) * 4;

    *(float4*)&Ws[0][skk * HID + sc4] = *(const float4*)&W[skk * HID + sc4];

    float acc[8][4];
#pragma unroll
    for (int r = 0; r < 8; ++r)
#pragma unroll
        for (int c = 0; c < 4; ++c) acc[r][c] = 0.f;

    int buf = 0;
    for (int k0 = 0; k0 < HID; k0 += 8) {
        float hr[8][8];
#pragma unroll
        for (int r = 0; r < 8; ++r) {
            int row = row0 + r; if (row >= n) row = n - 1;
            const float* hp = h + (size_t)row * HID + k0;
            float4 a = *(const float4*)hp;
            float4 b = *(const float4*)(hp + 4);
            hr[r][0] = a.x; hr[r][1] = a.y; hr[r][2] = a.z; hr[r][3] = a.w;
            hr[r][4] = b.x; hr[r][5] = b.y; hr[r][6] = b.z; hr[r][7] = b.w;
        }
        __syncthreads();
        if (k0 + 8 < HID)
            *(float4*)&Ws[buf ^ 1][skk * HID + sc4] =
                *(const float4*)&W[(k0 + 8 + skk) * HID + sc4];
#pragma unroll
        for (int kk = 0; kk < 8; ++kk) {
            float4 wv = *(const float4*)&Ws[buf][kk * HID + tc * 4];
#pragma unroll
            for (int r = 0; r < 8; ++r) {
                float hv = hr[r][kk];
                acc[r][0] = fmaf(hv, wv.x, acc[r][0]);
                acc[r][1] = fmaf(hv, wv.y, acc[r][1]);
                acc[r][2] = fmaf(hv, wv.z, acc[r][2]);
                acc[r][3] = fmaf(hv, wv.w, acc[r][3]);
            }
        }
        buf ^= 1;
    }
#pragma unroll
    for (int r = 0; r < 8; ++r) {
        int row = row0 + r;
        if (row < n) {
            float dd = dis[row];
            float4 o;
            o.x = dd * acc[r][0]; o.y = dd * acc[r][1];
            o.z = dd * acc[r][2]; o.w = dd * acc[r][3];
            *(float4*)&out[(size_t)row * HID + tc * 4] = o;
        }
    }
}

// --- aggregation, 2 dst per wave (8 loads in flight), on pre-scaled t.
// out[d] = relu(dis[d]*(t[d]+sum_{s in N(d)} t[s]) + b); POOL: atomicAdd into fpsum.
template <bool POOL>
__global__ __launch_bounds__(256) void k_agg2(const float* __restrict__ t,
                                              const float* __restrict__ dis,
                                              const int* __restrict__ rowst,
                                              const int* __restrict__ col,
                                              const float* __restrict__ bias,
                                              const int* __restrict__ batch,
                                              float* __restrict__ fpsum,
                                              float* __restrict__ outp) {
    int lane = threadIdx.x & 63;
    int wid  = threadIdx.x >> 6;
    int d0 = blockIdx.x * 8 + wid * 2;   // grid = N/8 = 6250 exactly; d1 = d0+1 < N
    int d1 = d0 + 1;
    const float2* t2 = (const float2*)t;
    float2 bv = ((const float2*)bias)[lane];
    float dd0 = dis[d0], dd1 = dis[d1];
    int a0 = rowst[d0], a1 = rowst[d1], b1 = rowst[d1 + 1];  // a1 is both A-end and B-start
    float2 sA = t2[(size_t)d0 * 64 + lane];
    float2 sB = t2[(size_t)d1 * 64 + lane];
    float xA0 = sA.x, yA0 = sA.y, xA1 = 0.f, yA1 = 0.f, xA2 = 0.f, yA2 = 0.f, xA3 = 0.f, yA3 = 0.f;
    float xB0 = sB.x, yB0 = sB.y, xB1 = 0.f, yB1 = 0.f, xB2 = 0.f, yB2 = 0.f, xB3 = 0.f, yB3 = 0.f;
    int ja = a0, jb = a1;
    // joint 4+4 unroll: 8 independent row loads in flight
    while (ja + 3 < a1 && jb + 3 < b1) {
        int sa0 = col[ja], sa1 = col[ja + 1], sa2 = col[ja + 2], sa3 = col[ja + 3];
        int sb0 = col[jb], sb1 = col[jb + 1], sb2 = col[jb + 2], sb3 = col[jb + 3];
        float2 vA0 = t2[(size_t)sa0 * 64 + lane];
        float2 vA1 = t2[(size_t)sa1 * 64 + lane];
        float2 vA2 = t2[(size_t)sa2 * 64 + lane];
        float2 vA3 = t2[(size_t)sa3 * 64 + lane];
        float2 vB0 = t2[(size_t)sb0 * 64 + lane];
        float2 vB1 = t2[(size_t)sb1 * 64 + lane];
        float2 vB2 = t2[(size_t)sb2 * 64 + lane];
        float2 vB3 = t2[(size_t)sb3 * 64 + lane];
        xA0 += vA0.x; yA0 += vA0.y; xA1 += vA1.x; yA1 += vA1.y;
        xA2 += vA2.x; yA2 += vA2.y; xA3 += vA3.x; yA3 += vA3.y;
        xB0 += vB0.x; yB0 += vB0.y; xB1 += vB1.x; yB1 += vB1.y;
        xB2 += vB2.x; yB2 += vB2.y; xB3 += vB3.x; yB3 += vB3.y;
        ja += 4; jb += 4;
    }
    for (; ja + 3 < a1; ja += 4) {
        int sa0 = col[ja], sa1 = col[ja + 1], sa2 = col[ja + 2], sa3 = col[ja + 3];
        float2 vA0 = t2[(size_t)sa0 * 64 + lane];
        float2 vA1 = t2[(size_t)sa1 * 64 + lane];
        float2 vA2 = t2[(size_t)sa2 * 64 + lane];
        float2 vA3 = t2[(size_t)sa3 * 64 + lane];
        xA0 += vA0.x; yA0 += vA0.y; xA1 += vA1.x; yA1 += vA1.y;
        xA2 += vA2.x; yA2 += vA2.y; xA3 += vA3.x; yA3 += vA3.y;
    }
    for (; jb + 3 < b1; jb += 4) {
        int sb0 = col[jb], sb1 = col[jb + 1], sb2 = col[jb + 2], sb3 = col[jb + 3];
        float2 vB0 = t2[(size_t)sb0 * 64 + lane];
        float2 vB1 = t2[(size_t)sb1 * 64 + lane];
        float2 vB2 = t2[(size_t)sb2 * 64 + lane];
        float2 vB3 = t2[(size_t)sb3 * 64 + lane];
        xB0 += vB0.x; yB0 += vB0.y; xB1 += vB1.x; yB1 += vB1.y;
        xB2 += vB2.x; yB2 += vB2.y; xB3 += vB3.x; yB3 += vB3.y;
    }
    for (; ja < a1; ++ja) {
        float2 v = t2[(size_t)col[ja] * 64 + lane];
        xA0 += v.x; yA0 += v.y;
    }
    for (; jb < b1; ++jb) {
        float2 v = t2[(size_t)col[jb] * 64 + lane];
        xB0 += v.x; yB0 += v.y;
    }
    float sxA = (xA0 + xA1) + (xA2 + xA3);
    float syA = (yA0 + yA1) + (yA2 + yA3);
    float sxB = (xB0 + xB1) + (xB2 + xB3);
    float syB = (yB0 + yB1) + (yB2 + yB3);
    float zxA = fmaxf(fmaf(dd0, sxA, bv.x), 0.f);
    float zyA = fmaxf(fmaf(dd0, syA, bv.y), 0.f);
    float zxB = fmaxf(fmaf(dd1, sxB, bv.x), 0.f);
    float zyB = fmaxf(fmaf(dd1, syB, bv.y), 0.f);
    if (POOL) {
        int g0 = batch[d0], g1 = batch[d1];
        atomicAdd(&fpsum[g0 * HID + 2 * lane], zxA);
        atomicAdd(&fpsum[g0 * HID + 2 * lane + 1], zyA);
        atomicAdd(&fpsum[g1 * HID + 2 * lane], zxB);
        atomicAdd(&fpsum[g1 * HID + 2 * lane + 1], zyB);
    } else {
        float2 oA; oA.x = zxA; oA.y = zyA;
        float2 oB; oB.x = zxB; oB.y = zyB;
        ((float2*)outp)[(size_t)d0 * 64 + lane] = oA;
        ((float2*)outp)[(size_t)d1 * 64 + lane] = oB;
    }
}

// --- final linear with mean folded in ---
__global__ void k_final(const float* __restrict__ fpsum, const int* __restrict__ gcnt,
                        const float* __restrict__ Wl, const float* __restrict__ bl,
                        float* __restrict__ out) {
    int idx = blockIdx.x * blockDim.x + threadIdx.x;
    if (idx >= N_GRAPHS * N_CLASSES) return;
    int g = idx / N_CLASSES, c = idx % N_CLASSES;
    float inv = 1.0f / (float)max(gcnt[g], 1);
    float acc = bl[c];
    for (int f = 0; f < HID; ++f)
        acc = fmaf(fpsum[g * HID + f] * inv, Wl[f * N_CLASSES + c], acc);
    out[idx] = acc;
}

extern "C" void kernel_launch(void* const* d_in, const int* in_sizes, int n_in,
                              void* d_out, int out_size, void* d_ws, size_t ws_size,
                              hipStream_t stream) {
    const float* x     = (const float*)d_in[0];
    const int*   srcp  = (const int*)d_in[1];
    const int*   dstp  = (const int*)d_in[1] + N_EDGES;
    const int*   batch = (const int*)d_in[2];
    const float* W1 = (const float*)d_in[3];
    const float* b1 = (const float*)d_in[4];
    const float* W2 = (const float*)d_in[5];
    const float* b2 = (const float*)d_in[6];
    const float* W3 = (const float*)d_in[7];
    const float* b3 = (const float*)d_in[8];
    const float* Wl = (const float*)d_in[9];
    const float* bl = (const float*)d_in[10];
    float* out = (float*)d_out;

    const int N = N_NODES, E = N_EDGES;

    char* ws = (char*)d_ws;
    size_t off = 0;
    auto alloc = [&](size_t bytes) -> void* {
        void* p = ws + off;
        off += (bytes + 255) & ~(size_t)255;
        return p;
    };
    // zero-initialized region first & contiguous (ws is poisoned 0xAA each call)
    int*   ideg   = (int*)alloc((size_t)N * 4);
    int*   cursor = (int*)alloc((size_t)N * 4);
    float* fpsum  = (float*)alloc((size_t)N_GRAPHS * HID * 4);
    size_t zero_bytes = off;
    int*   gcnt  = (int*)alloc((size_t)N_GRAPHS * 4);
    float* dis   = (float*)alloc((size_t)N * 4);
    int*   rowst = (int*)alloc((size_t)(N + 1) * 4);
    int*   col   = (int*)alloc((size_t)E * 4);
    int*   bsum  = (int*)alloc((size_t)NCHUNK * 4);
    int*   boff  = (int*)alloc((size_t)(NCHUNK + 1) * 4);
    float* bufA  = (float*)alloc((size_t)N * HID * 4);
    float* bufB  = (float*)alloc((size_t)N * HID * 4);

    hipMemsetAsync(d_ws, 0, zero_bytes, stream);

    const int tpb = 256;
    k_deg<<<(E + tpb - 1) / tpb, tpb, 0, stream>>>(dstp, ideg, E);
    k_scan_part<<<NCHUNK, 256, 0, stream>>>(ideg, bsum, dis, N);
    k_scan_bsum_goff<<<1, 256, 0, stream>>>(bsum, boff, batch, gcnt);
    k_scan_write<<<NCHUNK, 256, 0, stream>>>(ideg, boff, rowst, N);
    // fill + layer-1 GEMM fused (independent work, one pass)
    k_fill_gin<<<N * 32 / tpb, tpb, 0, stream>>>(srcp, dstp, rowst, cursor, col,
                                                 x, W1, dis, bufA);
    // layer 1 agg
    k_agg2<false><<<N / 8, 256, 0, stream>>>(bufA, dis, rowst, col, b1, batch, fpsum, bufB);
    // layer 2
    k_gemm64<<<(N + 63) / 64, 256, 0, stream>>>(bufB, W2, dis, bufA, N);
    k_agg2<false><<<N / 8, 256, 0, stream>>>(bufA, dis, rowst, col, b2, batch, fpsum, bufB);
    // layer 3
    k_gemm64<<<(N + 63) / 64, 256, 0, stream>>>(bufB, W3, dis, bufA, N);
    k_agg2<true><<<N / 8, 256, 0, stream>>>(bufA, dis, rowst, col, b3, batch, fpsum, nullptr);
    // classifier
    k_final<<<(N_GRAPHS * N_CLASSES + tpb - 1) / tpb, tpb, 0, stream>>>(fpsum, gcnt, Wl, bl, out);
}